// Round 16
// baseline (117.998 us; speedup 1.0000x reference)
//
#include <hip/hip_runtime.h>
#include <math.h>

#define NI 256
#define NJ 256
#define NK 1024
#define JCHUNK 32
#define WPB 4
#define KSEG 256
#define WREG 288   // 16 left halo/pad + 256 own + 16 right halo (floats)

typedef float float4v __attribute__((ext_vector_type(4)));

__device__ __forceinline__ float finalize(float n, float d) {
    // semblance <= 1 (Cauchy-Schwarz): no overflow. 0/0 -> 0*inf = nan -> 1.0.
    float r = n * __builtin_amdgcn_rcpf(d);
    if (!(r == r)) r = 1.0f;
    return r;
}

// 20-wide sliding k-window, all-aligned b128 reads (conflict-free — R10 pattern).
// p0 points at float idx (own_base - 12) of the logical row.
__device__ __forceinline__ void kwindow(const float* __restrict__ p0,
                                        float& w0, float& w1, float& w2, float& w3) {
    const float4v* p = (const float4v*)p0;
    float4v q0 = p[0], q1 = p[1], q2 = p[2], q3 = p[3], q4 = p[4], q5 = p[5], q6 = p[6];
    float4v midv = (q1 + q2) + (q3 + q4);
    float mid = (midv[0] + midv[1]) + (midv[2] + midv[3]);
    w0 = q0[2] + q0[3] + mid + q5[0] + q5[1];
    w1 = w0 + q5[2] - q0[2];
    w2 = w1 + q5[3] - q0[3];
    w3 = w2 + q6[0] - q1[0];
}

__global__ __launch_bounds__(256)
void semblance_kernel(const float* __restrict__ x, float* __restrict__ out) {
    // wave-private regions, single-buffered: zero s_barriers in the kernel.
    __shared__ __align__(16) float lds[WPB][2][WREG];

    const int tid  = threadIdx.x;
    const int lane = tid & 63;
    const int wave = tid >> 6;
    const int i    = blockIdx.y;
    const int j0   = blockIdx.x * JCHUNK;
    const int k0s  = wave * KSEG;
    const int kb   = k0s + 4 * lane;       // this lane's first global k

    float* Pn = &lds[wave][0][0];
    float* Pd = &lds[wave][1][0];

    // halo duty: lanes 0-2 -> left quads (idx 4,8,12), lanes 3-5 -> right (272,276,280)
    const bool hal  = (lane < 6);
    const int  hidx = (lane < 3) ? (4 + 4 * lane) : (272 + 4 * (lane - 3));
    const int  hk   = k0s + hidx - 16;     // global k of halo quad
    const bool hok  = hal && (hk >= 0) && (hk < NK);

    // zero halo quads once (out-of-range ones stay zero forever)
    if (hal) {
        *(float4v*)(Pn + hidx) = (float4v)0.f;
        *(float4v*)(Pd + hidx) = (float4v)0.f;
    }

    const float* xi = x + (size_t)i * NJ * NK;
    const float* xk = xi + kb;
    const float* xh = xi + hk;             // only dereferenced when hok

    // main running sums + register ring over rows j0-2..j0+2
    float4v r0, r1, r2, r3, r4;
    r0 = (j0 - 2 >= 0) ? *(const float4v*)(xk + (size_t)(j0 - 2) * NK) : (float4v)0.f;
    r1 = (j0 - 1 >= 0) ? *(const float4v*)(xk + (size_t)(j0 - 1) * NK) : (float4v)0.f;
    r2 = *(const float4v*)(xk + (size_t)j0 * NK);
    r3 = (j0 + 1 < NJ) ? *(const float4v*)(xk + (size_t)(j0 + 1) * NK) : (float4v)0.f;
    r4 = (j0 + 2 < NJ) ? *(const float4v*)(xk + (size_t)(j0 + 2) * NK) : (float4v)0.f;
    float4v s = (r0 + r1) + (r2 + r3) + r4;
    float4v t = (r0 * r0 + r1 * r1) + (r2 * r2 + r3 * r3) + r4 * r4;

    // halo running sums (ring-less: outgoing row reloaded, L1-hot)
    float4v hs = (float4v)0.f, ht = (float4v)0.f;
    if (hok) {
        #pragma unroll
        for (int dj = -2; dj <= 2; ++dj) {
            const int r = j0 + dj;
            if (r >= 0 && r < NJ) {
                float4v v = *(const float4v*)(xh + (size_t)r * NK);
                hs += v; ht += v * v;
            }
        }
    }

    #pragma unroll 2
    for (int jj = 0; jj < JCHUNK; ++jj) {
        const int j = j0 + jj;

        // publish row j (own quad + halo quad)
        *(float4v*)(Pn + 16 + 4 * lane) = s * s;
        *(float4v*)(Pd + 16 + 4 * lane) = t;
        if (hok) {
            *(float4v*)(Pn + hidx) = hs * hs;
            *(float4v*)(Pd + hidx) = ht;
        }

        // issue next-row loads now; consumed only at iteration END -> the whole
        // LDS-read + compute + store phase hides their latency
        float4v n = (float4v)0.f, hn = (float4v)0.f, hm = (float4v)0.f;
        if (j + 3 < NJ) n = *(const float4v*)(xk + (size_t)(j + 3) * NK);
        if (hok) {
            if (j + 3 < NJ) hn = *(const float4v*)(xh + (size_t)(j + 3) * NK);
            if (j - 2 >= 0) hm = *(const float4v*)(xh + (size_t)(j - 2) * NK);
        }

        // wave-internal write->read ordering (DS pipe in-order per wave)
        __builtin_amdgcn_wave_barrier();
        asm volatile("" ::: "memory");

        float wn0, wn1, wn2, wn3, wd0, wd1, wd2, wd3;
        kwindow(Pn + 4 + 4 * lane, wn0, wn1, wn2, wn3);
        kwindow(Pd + 4 + 4 * lane, wd0, wd1, wd2, wd3);

        const int jlo = (j - 2 < 0) ? 0 : j - 2;
        const int jhi = (j + 2 > NJ - 1) ? NJ - 1 : j + 2;
        const float norm = (float)(jhi - jlo + 1);

        float4v o;
        o[0] = finalize(wn0, wd0 * norm);
        o[1] = finalize(wn1, wd1 * norm);
        o[2] = finalize(wn2, wd2 * norm);
        o[3] = finalize(wn3, wd3 * norm);
        // PLAIN store this round (A/B vs R10's nontemporal): the 6.3 TB/s copy
        // ceiling was measured with cacheable stores — isolate the store path.
        *(float4v*)(out + ((size_t)i * NJ + j) * NK + kb) = o;

        // slide running sums (vmcnt wait lands here, far from the issue point)
        s += n - r0;
        t += n * n - r0 * r0;
        r0 = r1; r1 = r2; r2 = r3; r3 = r4; r4 = n;
        if (hok) { hs += hn - hm; ht += hn * hn - hm * hm; }

        // order this iteration's LDS reads before next iteration's writes
        __builtin_amdgcn_wave_barrier();
        asm volatile("" ::: "memory");
    }
}

extern "C" void kernel_launch(void* const* d_in, const int* in_sizes, int n_in,
                              void* d_out, int out_size, void* d_ws, size_t ws_size,
                              hipStream_t stream) {
    const float* x = (const float*)d_in[0];
    float* out = (float*)d_out;
    dim3 grid(NJ / JCHUNK, NI);   // (8, 256) = 2048 blocks, 4 independent waves each
    semblance_kernel<<<grid, 256, 0, stream>>>(x, out);
}

// Round 17
// 97.046 us; speedup vs baseline: 1.2159x; 1.2159x over previous
//
#include <hip/hip_runtime.h>
#include <math.h>

#define NI 256
#define NJ 256
#define NK 1024
#define JCHUNK 16
#define WPB 4
#define KSEG 256
#define WREG 288   // 16 left halo/pad + 256 own + 16 right halo (floats)

typedef float float4v __attribute__((ext_vector_type(4)));

__device__ __forceinline__ float finalize(float n, float d) {
    // semblance <= 1 (Cauchy-Schwarz): no overflow. 0/0 -> 0*inf = nan -> 1.0.
    float r = n * __builtin_amdgcn_rcpf(d);
    if (!(r == r)) r = 1.0f;
    return r;
}

// 20-wide sliding k-window, all-aligned b128 reads (conflict-free — R10 pattern).
// p0 points at float idx (own_base - 12) of the logical row.
__device__ __forceinline__ void kwindow(const float* __restrict__ p0,
                                        float& w0, float& w1, float& w2, float& w3) {
    const float4v* p = (const float4v*)p0;
    float4v q0 = p[0], q1 = p[1], q2 = p[2], q3 = p[3], q4 = p[4], q5 = p[5], q6 = p[6];
    float4v midv = (q1 + q2) + (q3 + q4);
    float mid = (midv[0] + midv[1]) + (midv[2] + midv[3]);
    w0 = q0[2] + q0[3] + mid + q5[0] + q5[1];
    w1 = w0 + q5[2] - q0[2];
    w2 = w1 + q5[3] - q0[3];
    w3 = w2 + q6[0] - q1[0];
}

__global__ __launch_bounds__(256)
void semblance_kernel(const float* __restrict__ x, float* __restrict__ out) {
    // wave-private regions, single-buffered: zero s_barriers in the kernel.
    __shared__ __align__(16) float lds[WPB][2][WREG];

    const int tid  = threadIdx.x;
    const int lane = tid & 63;
    const int wave = tid >> 6;
    const int i    = blockIdx.y;
    const int j0   = blockIdx.x * JCHUNK;
    const int k0s  = wave * KSEG;
    const int kb   = k0s + 4 * lane;       // this lane's first global k

    float* Pn = &lds[wave][0][0];
    float* Pd = &lds[wave][1][0];

    // halo duty: lanes 0-2 -> left quads (idx 4,8,12), lanes 3-5 -> right (272,276,280)
    const bool hal  = (lane < 6);
    const int  hidx = (lane < 3) ? (4 + 4 * lane) : (272 + 4 * (lane - 3));
    const int  hk   = k0s + hidx - 16;     // global k of halo quad
    const bool hok  = hal && (hk >= 0) && (hk < NK);

    // zero halo quads once (out-of-range ones stay zero forever)
    if (hal) {
        *(float4v*)(Pn + hidx) = (float4v)0.f;
        *(float4v*)(Pd + hidx) = (float4v)0.f;
    }

    const float* xi = x + (size_t)i * NJ * NK;
    const float* xk = xi + kb;
    const float* xh = xi + hk;             // only dereferenced when hok

    // main running sums + register ring over rows j0-2..j0+2
    float4v r0, r1, r2, r3, r4;
    r0 = (j0 - 2 >= 0) ? *(const float4v*)(xk + (size_t)(j0 - 2) * NK) : (float4v)0.f;
    r1 = (j0 - 1 >= 0) ? *(const float4v*)(xk + (size_t)(j0 - 1) * NK) : (float4v)0.f;
    r2 = *(const float4v*)(xk + (size_t)j0 * NK);
    r3 = (j0 + 1 < NJ) ? *(const float4v*)(xk + (size_t)(j0 + 1) * NK) : (float4v)0.f;
    r4 = (j0 + 2 < NJ) ? *(const float4v*)(xk + (size_t)(j0 + 2) * NK) : (float4v)0.f;
    float4v s = (r0 + r1) + (r2 + r3) + r4;
    float4v t = (r0 * r0 + r1 * r1) + (r2 * r2 + r3 * r3) + r4 * r4;

    // halo running sums (ring-less: outgoing row reloaded, L1-hot)
    float4v hs = (float4v)0.f, ht = (float4v)0.f;
    if (hok) {
        #pragma unroll
        for (int dj = -2; dj <= 2; ++dj) {
            const int r = j0 + dj;
            if (r >= 0 && r < NJ) {
                float4v v = *(const float4v*)(xh + (size_t)r * NK);
                hs += v; ht += v * v;
            }
        }
    }

    #pragma unroll 2
    for (int jj = 0; jj < JCHUNK; ++jj) {
        const int j = j0 + jj;

        // publish row j (own quad + halo quad)
        *(float4v*)(Pn + 16 + 4 * lane) = s * s;
        *(float4v*)(Pd + 16 + 4 * lane) = t;
        if (hok) {
            *(float4v*)(Pn + hidx) = hs * hs;
            *(float4v*)(Pd + hidx) = ht;
        }

        // issue next-row loads now; consumed only at iteration END -> the whole
        // LDS-read + compute + store phase hides their latency
        float4v n = (float4v)0.f, hn = (float4v)0.f, hm = (float4v)0.f;
        if (j + 3 < NJ) n = *(const float4v*)(xk + (size_t)(j + 3) * NK);
        if (hok) {
            if (j + 3 < NJ) hn = *(const float4v*)(xh + (size_t)(j + 3) * NK);
            if (j - 2 >= 0) hm = *(const float4v*)(xh + (size_t)(j - 2) * NK);
        }

        // wave-internal write->read ordering (DS pipe in-order per wave)
        __builtin_amdgcn_wave_barrier();
        asm volatile("" ::: "memory");

        float wn0, wn1, wn2, wn3, wd0, wd1, wd2, wd3;
        kwindow(Pn + 4 + 4 * lane, wn0, wn1, wn2, wn3);
        kwindow(Pd + 4 + 4 * lane, wd0, wd1, wd2, wd3);

        const int jlo = (j - 2 < 0) ? 0 : j - 2;
        const int jhi = (j + 2 > NJ - 1) ? NJ - 1 : j + 2;
        const float norm = (float)(jhi - jlo + 1);

        float4v o;
        o[0] = finalize(wn0, wd0 * norm);
        o[1] = finalize(wn1, wd1 * norm);
        o[2] = finalize(wn2, wd2 * norm);
        o[3] = finalize(wn3, wd3 * norm);
        // nt store: keep the 268 MB output stream out of L3 (R16 A/B: worth 25 us)
        __builtin_nontemporal_store(o, (float4v*)(out + ((size_t)i * NJ + j) * NK + kb));

        // slide running sums (vmcnt wait lands here, far from the issue point)
        s += n - r0;
        t += n * n - r0 * r0;
        r0 = r1; r1 = r2; r2 = r3; r3 = r4; r4 = n;
        if (hok) { hs += hn - hm; ht += hn * hn - hm * hm; }

        // order this iteration's LDS reads before next iteration's writes
        __builtin_amdgcn_wave_barrier();
        asm volatile("" ::: "memory");
    }
}

extern "C" void kernel_launch(void* const* d_in, const int* in_sizes, int n_in,
                              void* d_out, int out_size, void* d_ws, size_t ws_size,
                              hipStream_t stream) {
    const float* x = (const float*)d_in[0];
    float* out = (float*)d_out;
    dim3 grid(NJ / JCHUNK, NI);   // (16, 256) = 4096 blocks, 4 independent waves each
    semblance_kernel<<<grid, 256, 0, stream>>>(x, out);
}

// Round 18
// 92.798 us; speedup vs baseline: 1.2716x; 1.0458x over previous
//
#include <hip/hip_runtime.h>
#include <math.h>

#define NI 256
#define NJ 256
#define NK 1024
#define JCHUNK 32
#define WPB 4
#define KSEG 256
#define WREG 288   // 16 left halo/pad + 256 own + 16 right halo (floats)

typedef float float4v __attribute__((ext_vector_type(4)));

__device__ __forceinline__ float finalize(float n, float d) {
    // semblance <= 1 (Cauchy-Schwarz): no overflow. 0/0 -> 0*inf = nan -> 1.0.
    float r = n * __builtin_amdgcn_rcpf(d);
    if (!(r == r)) r = 1.0f;
    return r;
}

// 20-wide sliding k-window, all-aligned b128 reads (conflict-free — R10 pattern).
// p0 points at float idx (own_base - 12) of the logical row.
__device__ __forceinline__ void kwindow(const float* __restrict__ p0,
                                        float& w0, float& w1, float& w2, float& w3) {
    const float4v* p = (const float4v*)p0;
    float4v q0 = p[0], q1 = p[1], q2 = p[2], q3 = p[3], q4 = p[4], q5 = p[5], q6 = p[6];
    float4v midv = (q1 + q2) + (q3 + q4);
    float mid = (midv[0] + midv[1]) + (midv[2] + midv[3]);
    w0 = q0[2] + q0[3] + mid + q5[0] + q5[1];
    w1 = w0 + q5[2] - q0[2];
    w2 = w1 + q5[3] - q0[3];
    w3 = w2 + q6[0] - q1[0];
}

__global__ __launch_bounds__(256)
void semblance_kernel(const float* __restrict__ x, float* __restrict__ out) {
    // wave-private regions, single-buffered: zero s_barriers in the kernel.
    __shared__ __align__(16) float lds[WPB][2][WREG];

    const int tid  = threadIdx.x;
    const int lane = tid & 63;
    const int wave = tid >> 6;
    const int i    = blockIdx.y;
    const int j0   = blockIdx.x * JCHUNK;
    const int k0s  = wave * KSEG;
    const int kb   = k0s + 4 * lane;       // this lane's first global k

    float* Pn = &lds[wave][0][0];
    float* Pd = &lds[wave][1][0];

    // halo duty: lanes 0-2 -> left quads (idx 4,8,12), lanes 3-5 -> right (272,276,280)
    const bool hal  = (lane < 6);
    const int  hidx = (lane < 3) ? (4 + 4 * lane) : (272 + 4 * (lane - 3));
    const int  hk   = k0s + hidx - 16;     // global k of halo quad
    const bool hok  = hal && (hk >= 0) && (hk < NK);

    // zero halo quads once (out-of-range ones stay zero forever)
    if (hal) {
        *(float4v*)(Pn + hidx) = (float4v)0.f;
        *(float4v*)(Pd + hidx) = (float4v)0.f;
    }

    const float* xi = x + (size_t)i * NJ * NK;
    const float* xk = xi + kb;
    const float* xh = xi + hk;             // only dereferenced when hok

    // main running sums + register ring over rows j0-2..j0+2
    float4v r0, r1, r2, r3, r4;
    r0 = (j0 - 2 >= 0) ? *(const float4v*)(xk + (size_t)(j0 - 2) * NK) : (float4v)0.f;
    r1 = (j0 - 1 >= 0) ? *(const float4v*)(xk + (size_t)(j0 - 1) * NK) : (float4v)0.f;
    r2 = *(const float4v*)(xk + (size_t)j0 * NK);
    r3 = (j0 + 1 < NJ) ? *(const float4v*)(xk + (size_t)(j0 + 1) * NK) : (float4v)0.f;
    r4 = (j0 + 2 < NJ) ? *(const float4v*)(xk + (size_t)(j0 + 2) * NK) : (float4v)0.f;
    float4v s = (r0 + r1) + (r2 + r3) + r4;
    float4v t = (r0 * r0 + r1 * r1) + (r2 * r2 + r3 * r3) + r4 * r4;

    // halo running sums (ring-less: outgoing row reloaded, L1-hot)
    float4v hs = (float4v)0.f, ht = (float4v)0.f;
    if (hok) {
        #pragma unroll
        for (int dj = -2; dj <= 2; ++dj) {
            const int r = j0 + dj;
            if (r >= 0 && r < NJ) {
                float4v v = *(const float4v*)(xh + (size_t)r * NK);
                hs += v; ht += v * v;
            }
        }
    }

    #pragma unroll 2
    for (int jj = 0; jj < JCHUNK; ++jj) {
        const int j = j0 + jj;

        // publish row j (own quad + halo quad)
        *(float4v*)(Pn + 16 + 4 * lane) = s * s;
        *(float4v*)(Pd + 16 + 4 * lane) = t;
        if (hok) {
            *(float4v*)(Pn + hidx) = hs * hs;
            *(float4v*)(Pd + hidx) = ht;
        }

        // issue next-row loads now; consumed only at iteration END -> the whole
        // LDS-read + compute + store phase hides their latency
        float4v n = (float4v)0.f, hn = (float4v)0.f, hm = (float4v)0.f;
        if (j + 3 < NJ) n = *(const float4v*)(xk + (size_t)(j + 3) * NK);
        if (hok) {
            if (j + 3 < NJ) hn = *(const float4v*)(xh + (size_t)(j + 3) * NK);
            if (j - 2 >= 0) hm = *(const float4v*)(xh + (size_t)(j - 2) * NK);
        }

        // wave-internal write->read ordering (DS pipe in-order per wave)
        __builtin_amdgcn_wave_barrier();
        asm volatile("" ::: "memory");

        float wn0, wn1, wn2, wn3, wd0, wd1, wd2, wd3;
        kwindow(Pn + 4 + 4 * lane, wn0, wn1, wn2, wn3);
        kwindow(Pd + 4 + 4 * lane, wd0, wd1, wd2, wd3);

        const int jlo = (j - 2 < 0) ? 0 : j - 2;
        const int jhi = (j + 2 > NJ - 1) ? NJ - 1 : j + 2;
        const float norm = (float)(jhi - jlo + 1);

        float4v o;
        o[0] = finalize(wn0, wd0 * norm);
        o[1] = finalize(wn1, wd1 * norm);
        o[2] = finalize(wn2, wd2 * norm);
        o[3] = finalize(wn3, wd3 * norm);
        // nt store: keep the 268 MB output stream out of L3 (R16 A/B: worth 25 us)
        __builtin_nontemporal_store(o, (float4v*)(out + ((size_t)i * NJ + j) * NK + kb));

        // slide running sums (vmcnt wait lands here, far from the issue point)
        s += n - r0;
        t += n * n - r0 * r0;
        r0 = r1; r1 = r2; r2 = r3; r3 = r4; r4 = n;
        if (hok) { hs += hn - hm; ht += hn * hn - hm * hm; }

        // order this iteration's LDS reads before next iteration's writes
        __builtin_amdgcn_wave_barrier();
        asm volatile("" ::: "memory");
    }
}

extern "C" void kernel_launch(void* const* d_in, const int* in_sizes, int n_in,
                              void* d_out, int out_size, void* d_ws, size_t ws_size,
                              hipStream_t stream) {
    const float* x = (const float*)d_in[0];
    float* out = (float*)d_out;
    dim3 grid(NJ / JCHUNK, NI);   // (8, 256) = 2048 blocks, 4 independent waves each
    semblance_kernel<<<grid, 256, 0, stream>>>(x, out);
}